// Round 4
// baseline (1219.185 us; speedup 1.0000x reference)
//
#include <hip/hip_runtime.h>
#include <cmath>

#define HD 512      // hidden
#define IN 512      // input features (K)
#define TT 784      // timesteps
#define BB 128      // batch
#define MH 50176    // rows per batch-half (64 * 784)

typedef short short8 __attribute__((ext_vector_type(8)));
typedef unsigned short ushort8 __attribute__((ext_vector_type(8)));
typedef float floatx4 __attribute__((ext_vector_type(4)));
typedef float floatx16 __attribute__((ext_vector_type(16)));

#define GLDS(gp, lp) __builtin_amdgcn_global_load_lds( \
    (const __attribute__((address_space(1))) void*)(gp), \
    (__attribute__((address_space(3))) void*)(lp), 16, 0, 0)

__device__ __forceinline__ unsigned short bf16_rne(float x) {
    unsigned u = __float_as_uint(x);
    unsigned r = u + 0x7FFFu + ((u >> 16) & 1u);
    return (unsigned short)(r >> 16);
}
__device__ __forceinline__ float bf16_f(unsigned short s) {
    return __uint_as_float(((unsigned)s) << 16);
}

// ---------------- split fp32 -> 3 bf16 planes (exact residual chain) --------
__global__ __launch_bounds__(256) void split3(
    const float* __restrict__ src, unsigned short* __restrict__ p1,
    unsigned short* __restrict__ p2, unsigned short* __restrict__ p3, long n8)
{
    long g = (long)blockIdx.x * 256 + threadIdx.x;
    if (g >= n8) return;
    const float* xp = src + g * 8;
    ushort8 o1, o2, o3;
#pragma unroll
    for (int j = 0; j < 8; ++j) {
        float x = xp[j];
        unsigned short s1 = bf16_rne(x);
        float r1 = x - bf16_f(s1);                 // exact in fp32
        unsigned short s2 = bf16_rne(r1);
        float r2 = r1 - bf16_f(s2);                // exact in fp32
        unsigned short s3 = bf16_rne(r2);
        o1[j] = s1; o2[j] = s2; o3[j] = s3;
    }
    *(ushort8*)(p1 + g * 8) = o1;
    *(ushort8*)(p2 + g * 8) = o2;
    *(ushort8*)(p3 + g * 8) = o3;
}

// ---------------- MFMA GEMM (bf16x3), pipelined no-drain schedule -----------
// d = X*W^T + bias;  X*W ~= a1b1 + (a1b2+a2b1) + (a1b3+a2b2+a3b1), fp32 accum.
// 128x128 tile, 4 waves (2M x 2N), per-wave 64x64 via 2x2 of 32x32x16 MFMA.
// BK=16, TRIPLE-buffered 72 KB dynamic LDS -> 2 blocks/CU preserved (the R2
// lesson), counted vmcnt(12) (never 0 in-loop), raw s_barrier (no drain),
// 16B-slot XOR swizzle (linear GLDS dest + pre-swizzled global src, rule #21),
// setprio(1) around the MFMA cluster. XCD-chunked remap kept from R3
// (FETCH 704->186 MB measured).
__global__ __launch_bounds__(256, 2) void gemm_bf16x3_p2(
    const unsigned short* __restrict__ Xp,   // [3][MH][512]
    const unsigned short* __restrict__ Wp,   // [3][1024][512]
    const float* __restrict__ b1, const float* __restrict__ b2,
    float* __restrict__ d1buf, float* __restrict__ d2buf)
{
    extern __shared__ unsigned short lds[];   // 3 x 12288 ushorts (72 KB)
    const int tid  = threadIdx.x;
    const int lane = tid & 63;
    const int w    = tid >> 6;
    // XCD-chunked remap: 3136 blocks = 8 chunks x 392 (bijective).
    const int wg = (blockIdx.x & 7) * 392 + (blockIdx.x >> 3);
    const int pm = wg >> 3;             // 0..391 over MH
    const int pn = wg & 7;              // 0..7 over N=1024 (fast -> A reuse)
    const int m0 = pm * 128;
    const int n0 = pn * 128;

    // ---- staging: 24 segments of 1 KB per buffer (32 rows x 16 cols of one
    // plane), 6 per wave. GLDS writes seg_base + lane*16B (linear). The 16B
    // col-half is pre-swizzled in the GLOBAL source: phys half (lane&1) holds
    // logical half (lane&1) ^ ((row>>2)&1), row = rb*32 + (lane>>1).
    const unsigned short* gp[6];
    unsigned loff[6];
    {
        const int rsub = lane >> 1;                        // row in 32-row seg
        const int csub = (((lane & 1) ^ ((lane >> 3) & 1)) * 8);
#pragma unroll
        for (int j = 0; j < 6; ++j) {
            int s = w * 6 + j;                             // 0..23
            int p = s >> 2, rb = s & 3;
            gp[j] = (p < 3)
              ? Xp + ((size_t)p * MH + m0 + rb * 32 + rsub) * IN + csub
              : Wp + ((size_t)(p - 3) * 1024 + n0 + rb * 32 + rsub) * IN + csub;
            loff[j] = (unsigned)s * 512;                   // ushort offset
        }
    }

    floatx16 acc[2][2];
#pragma unroll
    for (int i = 0; i < 2; ++i)
#pragma unroll
        for (int j = 0; j < 2; ++j)
#pragma unroll
            for (int r = 0; r < 16; ++r) acc[i][j][r] = 0.f;

    const int wm = w >> 1, wn = w & 1;                     // 2 x 2 waves
    const int l31 = lane & 31;
    // read-side swizzle: phys 16B slot = (lane>>5) ^ ((row>>2)&1); the row
    // bit2 equals (lane>>2)&1 for all our reads (base rows are mult. of 32).
    const int sl8 = (((lane >> 5) ^ ((lane >> 2) & 1)) & 1) * 8;

    auto compute = [&](const unsigned short* buf) {
        short8 A[2][3], B[2][3];
#pragma unroll
        for (int tt = 0; tt < 2; ++tt)
#pragma unroll
            for (int p = 0; p < 3; ++p) {
                A[tt][p] = *(const short8*)&buf[p * 2048 +
                    (wm * 64 + tt * 32 + l31) * 16 + sl8];
                B[tt][p] = *(const short8*)&buf[(3 + p) * 2048 +
                    (wn * 64 + tt * 32 + l31) * 16 + sl8];
            }
        __builtin_amdgcn_s_setprio(1);
#pragma unroll
        for (int ti = 0; ti < 2; ++ti)
#pragma unroll
            for (int tj = 0; tj < 2; ++tj) {
                floatx16 c = acc[ti][tj];
                c = __builtin_amdgcn_mfma_f32_32x32x16_bf16(A[ti][2], B[tj][0], c, 0, 0, 0);
                c = __builtin_amdgcn_mfma_f32_32x32x16_bf16(A[ti][1], B[tj][1], c, 0, 0, 0);
                c = __builtin_amdgcn_mfma_f32_32x32x16_bf16(A[ti][0], B[tj][2], c, 0, 0, 0);
                c = __builtin_amdgcn_mfma_f32_32x32x16_bf16(A[ti][1], B[tj][0], c, 0, 0, 0);
                c = __builtin_amdgcn_mfma_f32_32x32x16_bf16(A[ti][0], B[tj][1], c, 0, 0, 0);
                c = __builtin_amdgcn_mfma_f32_32x32x16_bf16(A[ti][0], B[tj][0], c, 0, 0, 0);
                acc[ti][tj] = c;
            }
        __builtin_amdgcn_s_setprio(0);
    };

#define STAGE(bb, t) do {                                            \
    _Pragma("unroll")                                                \
    for (int j = 0; j < 6; ++j)                                      \
        GLDS(gp[j] + (t) * 16, lds + (bb) + loff[j]);                \
    } while (0)

    // prologue: stage K-steps 0,1,2 into buffers 0,1,2 (18 GLDS in flight)
    STAGE(0,     0);
    STAGE(12288, 1);
    STAGE(24576, 2);

#pragma unroll 1
    for (int t = 0; t < 32; ++t) {                  // 32 K-steps of 16
        const int b = t - (t / 3) * 3;              // t % 3
        const int bb = b * 12288;
        if (t < 30)       asm volatile("s_waitcnt vmcnt(12)" ::: "memory");
        else if (t == 30) asm volatile("s_waitcnt vmcnt(6)"  ::: "memory");
        else              asm volatile("s_waitcnt vmcnt(0)"  ::: "memory");
        __builtin_amdgcn_s_barrier();               // all waves staged buf b
        __builtin_amdgcn_sched_barrier(0);
        compute(lds + bb);
        __builtin_amdgcn_sched_barrier(0);
        __builtin_amdgcn_s_barrier();               // all waves done reading b
        __builtin_amdgcn_sched_barrier(0);
        if (t < 29) STAGE(bb, t + 3);               // refill with step t+3
    }
#undef STAGE

    // epilogue: 32x32 C layout col=lane&31, row=(r&3)+8*(r>>2)+4*(lane>>5)
    // (m74/m101-verified)
    const int rhi = (lane >> 5) * 4;
    const bool first = (n0 < HD);
    const float* bias = first ? b1 : b2;
    float* obuf = first ? d1buf : d2buf;
    const int nb = n0 & (HD - 1);
    float bv[2];
#pragma unroll
    for (int tj = 0; tj < 2; ++tj) bv[tj] = bias[nb + wn * 64 + tj * 32 + l31];
#pragma unroll
    for (int ti = 0; ti < 2; ++ti) {
#pragma unroll
        for (int tj = 0; tj < 2; ++tj) {
            int n = nb + wn * 64 + tj * 32 + l31;
#pragma unroll
            for (int r = 0; r < 16; ++r) {
                int m = m0 + wm * 64 + ti * 32 + (r & 3) + 8 * (r >> 2) + rhi;
                obuf[(size_t)m * HD + n] = acc[ti][tj][r] + bv[tj];
            }
        }
    }
}

// ---------------- Scan: full T per (b,h), one batch-half per dispatch -------
// 2-group register ping-pong prefetch (R3, +14 us measured).
#define LOADG(g, A1, A2) do {                                        \
    _Pragma("unroll")                                                \
    for (int i = 0; i < 16; ++i) {                                   \
        A1[i] = p1[(size_t)((g) * 16 + i) * HD];                     \
        A2[i] = p2[(size_t)((g) * 16 + i) * HD];                     \
    } } while (0)

#define COMPG(g, A1, A2) do {                                        \
    unsigned int wq = 0;                                             \
    _Pragma("unroll")                                                \
    for (int i = 0; i < 16; ++i) {                                   \
        d1 = be1 * d1 + (1.f - be1) * A1[i];                         \
        d2 = be2 * d2 + (1.f - be2) * A2[i];                         \
        float tot = d1 + d2;                                         \
        mem = mem * alpha + (1.f - alpha) * tot - spk;               \
        bool fire = (mem - 1.0f) > 0.f;                              \
        spk = fire ? 1.f : 0.f;                                      \
        wq |= (fire ? 1u : 0u) << i;                                 \
    }                                                                \
    sp[(size_t)(g) * HD] = (unsigned short)wq; } while (0)

__global__ __launch_bounds__(64) void scan_half(
    const float* __restrict__ d1buf, const float* __restrict__ d2buf,
    const float* __restrict__ tau_m, const float* __restrict__ tau_n1,
    const float* __restrict__ tau_n2,
    const float* __restrict__ mem0, const float* __restrict__ spike0,
    unsigned short* __restrict__ spikes, int b0)
{
    const int gid = blockIdx.x * 64 + threadIdx.x;   // 0..32767
    const int h  = gid & (HD - 1);
    const int bl = gid >> 9;                          // local batch 0..63
    const int b  = b0 + bl;
    const float alpha = 1.f / (1.f + expf(-tau_m[h]));
    const float be1   = 1.f / (1.f + expf(-tau_n1[h]));
    const float be2   = 1.f / (1.f + expf(-tau_n2[h]));
    float mem = mem0[b * HD + h];
    float spk = spike0[b * HD + h];
    float d1 = 0.f, d2 = 0.f;
    const float* p1 = d1buf + (size_t)bl * TT * HD + h;
    const float* p2 = d2buf + (size_t)bl * TT * HD + h;
    unsigned short* sp = spikes + (size_t)b * (TT / 16) * HD + h;

    float a1A[16], a2A[16], a1B[16], a2B[16];
    LOADG(0, a1A, a2A);
#pragma unroll 1
    for (int g = 0; g < 48; g += 2) {       // 49 groups total (0..48)
        LOADG(g + 1, a1B, a2B);
        COMPG(g,     a1A, a2A);
        LOADG(g + 2, a1A, a2A);             // g+2 <= 48 always (g <= 46)
        COMPG(g + 1, a1B, a2B);
    }
    COMPG(48, a1A, a2A);
}

// ---------------- Readout (round-1/4 validated) -----------------------------
__global__ __launch_bounds__(256) void readout(
    const unsigned short* __restrict__ spikes,
    const float* __restrict__ Wr, const float* __restrict__ br,
    float* __restrict__ out)
{
    __shared__ float WrS[10 * HD];   // 20 KB, layout [o][h]
    __shared__ float brS[10];
    const int tid = threadIdx.x;
    for (int i = tid; i < 10 * HD; i += 256) WrS[i] = Wr[i];
    if (tid < 10) brS[tid] = br[tid];
    __syncthreads();

    const int gid = blockIdx.x * 256 + tid;      // 0..100351 = b*784+t
    const int t = gid % TT;
    const int b = gid / TT;
    const int tw  = t >> 4;
    const int bit = t & 15;
    const unsigned short* row = spikes + ((size_t)b * (TT / 16) + tw) * HD;

    float acc[10];
#pragma unroll
    for (int o = 0; o < 10; ++o) acc[o] = brS[o];

    for (int h = 0; h < HD; ++h) {
        float s = (float)((row[h] >> bit) & 1);
#pragma unroll
        for (int o = 0; o < 10; ++o) acc[o] = fmaf(s, WrS[o * HD + h], acc[o]);
    }
    float* op = out + (size_t)gid * 10;
#pragma unroll
    for (int o = 0; o < 10; ++o) op[o] = acc[o];
}

// ---------------------------------------------------------------------------
extern "C" void kernel_launch(void* const* d_in, const int* in_sizes, int n_in,
                              void* d_out, int out_size, void* d_ws, size_t ws_size,
                              hipStream_t stream)
{
    const float* X      = (const float*)d_in[0];
    const float* W1     = (const float*)d_in[1];
    const float* b1     = (const float*)d_in[2];
    const float* W2     = (const float*)d_in[3];
    const float* b2     = (const float*)d_in[4];
    const float* tau_m  = (const float*)d_in[5];
    const float* tau_n1 = (const float*)d_in[6];
    const float* tau_n2 = (const float*)d_in[7];
    const float* Wr     = (const float*)d_in[8];
    const float* br     = (const float*)d_in[9];
    const float* mem0   = (const float*)d_in[10];
    const float* spike0 = (const float*)d_in[11];
    float* out = (float*)d_out;

    // one-time: allow 72 KB dynamic LDS for the GEMM
    static int s_attr = 0;
    if (!s_attr) {
        (void)hipFuncSetAttribute(
            reinterpret_cast<const void*>(gemm_bf16x3_p2),
            hipFuncAttributeMaxDynamicSharedMemorySize, 73728);
        s_attr = 1;
    }

    // workspace: 3.1 (Wp) + 154.1 (Xp) + 205.5 (d) + 6.4 (spikes) = 369 MB
    char* p = (char*)d_ws;
    unsigned short* Wp = (unsigned short*)p;  p += (size_t)3 * 1024 * IN * 2;
    unsigned short* Xp = (unsigned short*)p;  p += (size_t)3 * MH * IN * 2;
    float* d1buf = (float*)p;                 p += (size_t)MH * HD * 4;
    float* d2buf = (float*)p;                 p += (size_t)MH * HD * 4;
    unsigned short* spikes = (unsigned short*)p;

    const size_t WPS = (size_t)1024 * IN;    // W plane stride (elems)
    const size_t XPS = (size_t)MH * IN;      // X plane stride (elems)

    // split W1 (plane rows 0..511) and W2 (rows 512..1023)
    split3<<<dim3(128), dim3(256), 0, stream>>>(
        W1, Wp, Wp + WPS, Wp + 2 * WPS, (long)HD * IN / 8);
    split3<<<dim3(128), dim3(256), 0, stream>>>(
        W2, Wp + (size_t)HD * IN, Wp + WPS + (size_t)HD * IN,
        Wp + 2 * WPS + (size_t)HD * IN, (long)HD * IN / 8);

    for (int half = 0; half < 2; ++half) {
        split3<<<dim3((unsigned)(((long)MH * IN / 8 + 255) / 256)), dim3(256), 0, stream>>>(
            X + (size_t)half * MH * IN, Xp, Xp + XPS, Xp + 2 * XPS, (long)MH * IN / 8);
        gemm_bf16x3_p2<<<dim3(392 * 8), dim3(256), 73728, stream>>>(
            Xp, Wp, b1, b2, d1buf, d2buf);
        scan_half<<<dim3(512), dim3(64), 0, stream>>>(
            d1buf, d2buf, tau_m, tau_n1, tau_n2, mem0, spike0,
            spikes, half * 64);
    }
    readout<<<dim3(BB * TT / 256), dim3(256), 0, stream>>>(spikes, Wr, br, out);
}

// Round 5
// 937.776 us; speedup vs baseline: 1.3001x; 1.3001x over previous
//
#include <hip/hip_runtime.h>
#include <cmath>

#define HD 512      // hidden
#define IN 512      // input features (K)
#define TT 784      // timesteps
#define BB 128      // batch
#define MH 50176    // rows per batch-half (64 * 784)

typedef short short8 __attribute__((ext_vector_type(8)));
typedef unsigned short ushort8 __attribute__((ext_vector_type(8)));
typedef float floatx4 __attribute__((ext_vector_type(4)));
typedef unsigned int uintx4 __attribute__((ext_vector_type(4)));

#define GLDS(gp, lp) __builtin_amdgcn_global_load_lds( \
    (const __attribute__((address_space(1))) void*)(gp), \
    (__attribute__((address_space(3))) void*)(lp), 16, 0, 0)

// hw packed cvt: dst.lo16 = bf16_rne(a), dst.hi16 = bf16_rne(b)
#define CVTPK(d, a, b) asm("v_cvt_pk_bf16_f32 %0, %1, %2" : "=v"(d) : "v"(a), "v"(b))

__device__ __forceinline__ unsigned short bf16_rne(float x) {
    unsigned u = __float_as_uint(x);
    unsigned r = u + 0x7FFFu + ((u >> 16) & 1u);
    return (unsigned short)(r >> 16);
}
__device__ __forceinline__ float bf16_f(unsigned short s) {
    return __uint_as_float(((unsigned)s) << 16);
}

// ---------------- split fp32 -> 3 bf16 planes (W only now) ------------------
__global__ __launch_bounds__(256) void split3(
    const float* __restrict__ src, unsigned short* __restrict__ p1,
    unsigned short* __restrict__ p2, unsigned short* __restrict__ p3, long n8)
{
    long g = (long)blockIdx.x * 256 + threadIdx.x;
    if (g >= n8) return;
    const float* xp = src + g * 8;
    ushort8 o1, o2, o3;
#pragma unroll
    for (int j = 0; j < 8; ++j) {
        float x = xp[j];
        unsigned short s1 = bf16_rne(x);
        float r1 = x - bf16_f(s1);                 // exact in fp32
        unsigned short s2 = bf16_rne(r1);
        float r2 = r1 - bf16_f(s2);                // exact in fp32
        unsigned short s3 = bf16_rne(r2);
        o1[j] = s1; o2[j] = s2; o3[j] = s3;
    }
    *(ushort8*)(p1 + g * 8) = o1;
    *(ushort8*)(p2 + g * 8) = o2;
    *(ushort8*)(p3 + g * 8) = o3;
}

// ---------------- MFMA GEMM (bf16x3) with fused on-the-fly X split ----------
// d = X*W^T + bias;  X*W ~= a1b1 + (a1b2+a2b1) + (a1b3+a2b2+a3b1), fp32 accum.
// 128x128 tile, 4 waves of 64x64, 16x16x32 MFMA, K-step 32. 48 KB LDS,
// 2 blocks/CU (the R0/R3 proven operating point; R2/R4 showed pipelined
// 1-block variants regress). A: fp32 X loaded to regs (prefetched 1 K-step
// ahead), split to 3 bf16 planes via v_cvt_pk_bf16_f32 (exact residual
// chain, same numerics as split3), ds_write to LDS. B: GLDS from pre-split
// Wp. Raw s_barrier + counted vmcnt(4) keeps the 4 A prefetch loads alive
// across barriers. XCD-chunked remap kept (FETCH 704->186 MB measured R3).
__global__ __launch_bounds__(256, 2) void gemm_fused(
    const float* __restrict__ Xf,            // [MH][512] fp32 (batch-half)
    const unsigned short* __restrict__ Wp,   // [3][1024][512] bf16 planes
    const float* __restrict__ b1, const float* __restrict__ b2,
    float* __restrict__ d1buf, float* __restrict__ d2buf)
{
    __shared__ unsigned short lds[6][128][32];   // A1,A2,A3,B1,B2,B3
    unsigned short* lflat = &lds[0][0][0];
    const int tid  = threadIdx.x;
    const int lane = tid & 63;
    const int w    = tid >> 6;
    // XCD-chunked remap: 3136 blocks = 8 chunks x 392 (bijective).
    const int wg = (blockIdx.x & 7) * 392 + (blockIdx.x >> 3);
    const int pm = wg >> 3;             // 0..391 over MH
    const int pn = wg & 7;              // 0..7 over N=1024 (fast -> A reuse)
    const int m0 = pm * 128;
    const int n0 = pn * 128;

    // ---- B staging (GLDS): 24 segments of 1 KB (16 rows x 32 cols), 6/wave
    const unsigned short* gpb[6];
    unsigned lofb[6];
    {
        const int rsub = lane >> 2;          // row within 16-row segment
        const int csub = (lane & 3) * 8;     // ushort offset within row
#pragma unroll
        for (int j = 0; j < 6; ++j) {
            int s = w * 6 + j;               // 0..23
            int p = s >> 3, sub = s & 7;
            gpb[j] = Wp + ((size_t)p * 1024 + n0 + sub * 16 + rsub) * IN + csub;
            lofb[j] = 12288u + (unsigned)s * 512;   // B region starts plane 3
        }
    }

    // ---- A staging (regs): thread -> row = tid>>1, k-half = tid&1
    const int arow  = tid >> 1;
    const int ahalf = tid & 1;
    const float* ga = Xf + (size_t)(m0 + arow) * IN + ahalf * 16;
    const int awbase = arow * 32 + ahalf * 16;   // ushort index within plane

    floatx4 acc[4][4];
#pragma unroll
    for (int i = 0; i < 4; ++i)
#pragma unroll
        for (int j = 0; j < 4; ++j) acc[i][j] = (floatx4){0.f, 0.f, 0.f, 0.f};

    const int wm = w >> 1, wn = w & 1;
    const int c16 = lane & 15;
    const int q8  = (lane >> 4) * 8;

#define LOADA(DST, T) do {                                           \
    _Pragma("unroll")                                                \
    for (int q = 0; q < 4; ++q)                                      \
        DST[q] = *(const floatx4*)(ga + (T) * 32 + q * 4);           \
    } while (0)

    // split 16 fp32 -> 3 planes x 16 bf16, write to LDS (exact residual
    // chain; hw cvt_pk is RNE = split3's bf16_rne)
#define SPLITW(SRC) do {                                             \
    unsigned w1[8], w2[8], w3[8];                                    \
    _Pragma("unroll")                                                \
    for (int q = 0; q < 4; ++q) {                                    \
        _Pragma("unroll")                                            \
        for (int e = 0; e < 2; ++e) {                                \
            float x0 = SRC[q][e * 2], x1 = SRC[q][e * 2 + 1];        \
            unsigned pk1, pk2, pk3;                                  \
            CVTPK(pk1, x0, x1);                                      \
            float r0 = x0 - __uint_as_float(pk1 << 16);              \
            float r1 = x1 - __uint_as_float(pk1 & 0xFFFF0000u);      \
            CVTPK(pk2, r0, r1);                                      \
            float s0 = r0 - __uint_as_float(pk2 << 16);              \
            float s1 = r1 - __uint_as_float(pk2 & 0xFFFF0000u);      \
            CVTPK(pk3, s0, s1);                                      \
            w1[q * 2 + e] = pk1; w2[q * 2 + e] = pk2; w3[q * 2 + e] = pk3; \
        }                                                            \
    }                                                                \
    *(uintx4*)(lflat + awbase)            = (uintx4){w1[0], w1[1], w1[2], w1[3]}; \
    *(uintx4*)(lflat + awbase + 8)        = (uintx4){w1[4], w1[5], w1[6], w1[7]}; \
    *(uintx4*)(lflat + 4096 + awbase)     = (uintx4){w2[0], w2[1], w2[2], w2[3]}; \
    *(uintx4*)(lflat + 4096 + awbase + 8) = (uintx4){w2[4], w2[5], w2[6], w2[7]}; \
    *(uintx4*)(lflat + 8192 + awbase)     = (uintx4){w3[0], w3[1], w3[2], w3[3]}; \
    *(uintx4*)(lflat + 8192 + awbase + 8) = (uintx4){w3[4], w3[5], w3[6], w3[7]}; \
    } while (0)

#define COMPUTE() do {                                               \
    short8 Bf[3][4];                                                 \
    _Pragma("unroll")                                                \
    for (int p = 0; p < 3; ++p)                                      \
        _Pragma("unroll")                                            \
        for (int fj = 0; fj < 4; ++fj)                               \
            Bf[p][fj] = *(const short8*)&lds[3 + p][wn * 64 + fj * 16 + c16][q8]; \
    _Pragma("unroll")                                                \
    for (int fi = 0; fi < 4; ++fi) {                                 \
        const int r = wm * 64 + fi * 16 + c16;                       \
        short8 a1 = *(const short8*)&lds[0][r][q8];                  \
        short8 a2 = *(const short8*)&lds[1][r][q8];                  \
        short8 a3 = *(const short8*)&lds[2][r][q8];                  \
        _Pragma("unroll")                                            \
        for (int fj = 0; fj < 4; ++fj) {                             \
            floatx4 c = acc[fi][fj];                                 \
            c = __builtin_amdgcn_mfma_f32_16x16x32_bf16(a3, Bf[0][fj], c, 0, 0, 0); \
            c = __builtin_amdgcn_mfma_f32_16x16x32_bf16(a2, Bf[1][fj], c, 0, 0, 0); \
            c = __builtin_amdgcn_mfma_f32_16x16x32_bf16(a1, Bf[2][fj], c, 0, 0, 0); \
            c = __builtin_amdgcn_mfma_f32_16x16x32_bf16(a2, Bf[0][fj], c, 0, 0, 0); \
            c = __builtin_amdgcn_mfma_f32_16x16x32_bf16(a1, Bf[1][fj], c, 0, 0, 0); \
            c = __builtin_amdgcn_mfma_f32_16x16x32_bf16(a1, Bf[0][fj], c, 0, 0, 0); \
            acc[fi][fj] = c;                                         \
        }                                                            \
    } } while (0)

#define BAR() asm volatile("s_barrier" ::: "memory")

    floatx4 xa[4], xb[4];
    LOADA(xa, 0);                        // prefetch K-step 0

#pragma unroll 1
    for (int tp = 0; tp < 8; ++tp) {
        const int t0 = tp * 2, t1 = tp * 2 + 1;
        // ---- stage even step (regs xa), prefetch t1 into xb
#pragma unroll
        for (int j = 0; j < 6; ++j) GLDS(gpb[j] + t0 * 32, lflat + lofb[j]);
        LOADA(xb, t1);
        SPLITW(xa);
        asm volatile("s_waitcnt vmcnt(4) lgkmcnt(0)" ::: "memory");
        BAR();
        COMPUTE();
        BAR();
        // ---- stage odd step (regs xb), prefetch t1+1 into xa
#pragma unroll
        for (int j = 0; j < 6; ++j) GLDS(gpb[j] + t1 * 32, lflat + lofb[j]);
        if (tp < 7) LOADA(xa, t1 + 1);
        SPLITW(xb);
        if (tp < 7) asm volatile("s_waitcnt vmcnt(4) lgkmcnt(0)" ::: "memory");
        else        asm volatile("s_waitcnt vmcnt(0) lgkmcnt(0)" ::: "memory");
        BAR();
        COMPUTE();
        BAR();
    }
#undef LOADA
#undef SPLITW
#undef COMPUTE
#undef BAR

    // epilogue: C layout col=lane&15, row=(lane>>4)*4+reg (m89-verified)
    const int quad = lane >> 4;
    const bool first = (n0 < HD);
    const float* bias = first ? b1 : b2;
    float* obuf = first ? d1buf : d2buf;
    const int nb = n0 & (HD - 1);
    float bv[4];
#pragma unroll
    for (int fj = 0; fj < 4; ++fj) bv[fj] = bias[nb + wn * 64 + fj * 16 + c16];
#pragma unroll
    for (int fi = 0; fi < 4; ++fi) {
#pragma unroll
        for (int fj = 0; fj < 4; ++fj) {
            int n = nb + wn * 64 + fj * 16 + c16;
#pragma unroll
            for (int r = 0; r < 4; ++r) {
                int m = m0 + wm * 64 + fi * 16 + quad * 4 + r;
                obuf[(size_t)m * HD + n] = acc[fi][fj][r] + bv[fj];
            }
        }
    }
}

// ---------------- Scan: full T per (b,h), one batch-half per dispatch -------
// 2-group register ping-pong prefetch (R3, +14 us measured).
#define LOADG(g, A1, A2) do {                                        \
    _Pragma("unroll")                                                \
    for (int i = 0; i < 16; ++i) {                                   \
        A1[i] = p1[(size_t)((g) * 16 + i) * HD];                     \
        A2[i] = p2[(size_t)((g) * 16 + i) * HD];                     \
    } } while (0)

#define COMPG(g, A1, A2) do {                                        \
    unsigned int wq = 0;                                             \
    _Pragma("unroll")                                                \
    for (int i = 0; i < 16; ++i) {                                   \
        d1 = be1 * d1 + (1.f - be1) * A1[i];                         \
        d2 = be2 * d2 + (1.f - be2) * A2[i];                         \
        float tot = d1 + d2;                                         \
        mem = mem * alpha + (1.f - alpha) * tot - spk;               \
        bool fire = (mem - 1.0f) > 0.f;                              \
        spk = fire ? 1.f : 0.f;                                      \
        wq |= (fire ? 1u : 0u) << i;                                 \
    }                                                                \
    sp[(size_t)(g) * HD] = (unsigned short)wq; } while (0)

__global__ __launch_bounds__(64) void scan_half(
    const float* __restrict__ d1buf, const float* __restrict__ d2buf,
    const float* __restrict__ tau_m, const float* __restrict__ tau_n1,
    const float* __restrict__ tau_n2,
    const float* __restrict__ mem0, const float* __restrict__ spike0,
    unsigned short* __restrict__ spikes, int b0)
{
    const int gid = blockIdx.x * 64 + threadIdx.x;   // 0..32767
    const int h  = gid & (HD - 1);
    const int bl = gid >> 9;                          // local batch 0..63
    const int b  = b0 + bl;
    const float alpha = 1.f / (1.f + expf(-tau_m[h]));
    const float be1   = 1.f / (1.f + expf(-tau_n1[h]));
    const float be2   = 1.f / (1.f + expf(-tau_n2[h]));
    float mem = mem0[b * HD + h];
    float spk = spike0[b * HD + h];
    float d1 = 0.f, d2 = 0.f;
    const float* p1 = d1buf + (size_t)bl * TT * HD + h;
    const float* p2 = d2buf + (size_t)bl * TT * HD + h;
    unsigned short* sp = spikes + (size_t)b * (TT / 16) * HD + h;

    float a1A[16], a2A[16], a1B[16], a2B[16];
    LOADG(0, a1A, a2A);
#pragma unroll 1
    for (int g = 0; g < 48; g += 2) {       // 49 groups total (0..48)
        LOADG(g + 1, a1B, a2B);
        COMPG(g,     a1A, a2A);
        LOADG(g + 2, a1A, a2A);             // g+2 <= 48 always (g <= 46)
        COMPG(g + 1, a1B, a2B);
    }
    COMPG(48, a1A, a2A);
}

// ---------------- Readout (round-1/4 validated) -----------------------------
__global__ __launch_bounds__(256) void readout(
    const unsigned short* __restrict__ spikes,
    const float* __restrict__ Wr, const float* __restrict__ br,
    float* __restrict__ out)
{
    __shared__ float WrS[10 * HD];   // 20 KB, layout [o][h]
    __shared__ float brS[10];
    const int tid = threadIdx.x;
    for (int i = tid; i < 10 * HD; i += 256) WrS[i] = Wr[i];
    if (tid < 10) brS[tid] = br[tid];
    __syncthreads();

    const int gid = blockIdx.x * 256 + tid;      // 0..100351 = b*784+t
    const int t = gid % TT;
    const int b = gid / TT;
    const int tw  = t >> 4;
    const int bit = t & 15;
    const unsigned short* row = spikes + ((size_t)b * (TT / 16) + tw) * HD;

    float acc[10];
#pragma unroll
    for (int o = 0; o < 10; ++o) acc[o] = brS[o];

    for (int h = 0; h < HD; ++h) {
        float s = (float)((row[h] >> bit) & 1);
#pragma unroll
        for (int o = 0; o < 10; ++o) acc[o] = fmaf(s, WrS[o * HD + h], acc[o]);
    }
    float* op = out + (size_t)gid * 10;
#pragma unroll
    for (int o = 0; o < 10; ++o) op[o] = acc[o];
}

// ---------------------------------------------------------------------------
extern "C" void kernel_launch(void* const* d_in, const int* in_sizes, int n_in,
                              void* d_out, int out_size, void* d_ws, size_t ws_size,
                              hipStream_t stream)
{
    const float* X      = (const float*)d_in[0];
    const float* W1     = (const float*)d_in[1];
    const float* b1     = (const float*)d_in[2];
    const float* W2     = (const float*)d_in[3];
    const float* b2     = (const float*)d_in[4];
    const float* tau_m  = (const float*)d_in[5];
    const float* tau_n1 = (const float*)d_in[6];
    const float* tau_n2 = (const float*)d_in[7];
    const float* Wr     = (const float*)d_in[8];
    const float* br     = (const float*)d_in[9];
    const float* mem0   = (const float*)d_in[10];
    const float* spike0 = (const float*)d_in[11];
    float* out = (float*)d_out;

    // workspace: 3.1 (Wp) + 205.5 (d) + 6.4 (spikes) = 215 MB
    char* p = (char*)d_ws;
    unsigned short* Wp = (unsigned short*)p;  p += (size_t)3 * 1024 * IN * 2;
    float* d1buf = (float*)p;                 p += (size_t)MH * HD * 4;
    float* d2buf = (float*)p;                 p += (size_t)MH * HD * 4;
    unsigned short* spikes = (unsigned short*)p;

    const size_t WPS = (size_t)1024 * IN;    // W plane stride (elems)

    // split W1 (plane rows 0..511) and W2 (rows 512..1023)
    split3<<<dim3(128), dim3(256), 0, stream>>>(
        W1, Wp, Wp + WPS, Wp + 2 * WPS, (long)HD * IN / 8);
    split3<<<dim3(128), dim3(256), 0, stream>>>(
        W2, Wp + (size_t)HD * IN, Wp + WPS + (size_t)HD * IN,
        Wp + 2 * WPS + (size_t)HD * IN, (long)HD * IN / 8);

    for (int half = 0; half < 2; ++half) {
        gemm_fused<<<dim3(392 * 8), dim3(256), 0, stream>>>(
            X + (size_t)half * MH * IN, Wp, b1, b2, d1buf, d2buf);
        scan_half<<<dim3(512), dim3(64), 0, stream>>>(
            d1buf, d2buf, tau_m, tau_n1, tau_n2, mem0, spike0,
            spikes, half * 64);
    }
    readout<<<dim3(BB * TT / 256), dim3(256), 0, stream>>>(spikes, Wr, br, out);
}

// Round 8
// 912.485 us; speedup vs baseline: 1.3361x; 1.0277x over previous
//
#include <hip/hip_runtime.h>
#include <cmath>

#define HD 512      // hidden
#define IN 512      // input features (K)
#define TT 784      // timesteps
#define BB 128      // batch
#define MH 50176    // rows per batch-half (64 * 784)
#define MF 100352   // rows full batch (128 * 784)

typedef short short8 __attribute__((ext_vector_type(8)));
typedef unsigned short ushort8 __attribute__((ext_vector_type(8)));
typedef float floatx4 __attribute__((ext_vector_type(4)));
typedef unsigned int uintx4 __attribute__((ext_vector_type(4)));

#define GLDS(gp, lp) __builtin_amdgcn_global_load_lds( \
    (const __attribute__((address_space(1))) void*)(gp), \
    (__attribute__((address_space(3))) void*)(lp), 16, 0, 0)

// hw packed cvt: dst.lo16 = bf16_rne(a), dst.hi16 = bf16_rne(b)
#define CVTPK(d, a, b) asm("v_cvt_pk_bf16_f32 %0, %1, %2" : "=v"(d) : "v"(a), "v"(b))

__device__ __forceinline__ unsigned short bf16_rne(float x) {
    unsigned u = __float_as_uint(x);
    unsigned r = u + 0x7FFFu + ((u >> 16) & 1u);
    return (unsigned short)(r >> 16);
}
__device__ __forceinline__ float bf16_f(unsigned short s) {
    return __uint_as_float(((unsigned)s) << 16);
}

// ---------------- split fp32 -> 3 bf16 planes (W only) ----------------------
__global__ __launch_bounds__(256) void split3(
    const float* __restrict__ src, unsigned short* __restrict__ p1,
    unsigned short* __restrict__ p2, unsigned short* __restrict__ p3, long n8)
{
    long g = (long)blockIdx.x * 256 + threadIdx.x;
    if (g >= n8) return;
    const float* xp = src + g * 8;
    ushort8 o1, o2, o3;
#pragma unroll
    for (int j = 0; j < 8; ++j) {
        float x = xp[j];
        unsigned short s1 = bf16_rne(x);
        float r1 = x - bf16_f(s1);                 // exact in fp32
        unsigned short s2 = bf16_rne(r1);
        float r2 = r1 - bf16_f(s2);                // exact in fp32
        unsigned short s3 = bf16_rne(r2);
        o1[j] = s1; o2[j] = s2; o3[j] = s3;
    }
    *(ushort8*)(p1 + g * 8) = o1;
    *(ushort8*)(p2 + g * 8) = o2;
    *(ushort8*)(p3 + g * 8) = o3;
}

// ---------------- MFMA GEMM (bf16x3) with fused on-the-fly X split ----------
// NUMERICS FROZEN (R6/R7 lesson): d must be produced by R5's exact FMA
// sequence — 16x16x32 MFMA, product order a3b1,a2b2,a1b3,a2b1,a1b2,a1b1 per
// K=32 step, K ascending. Any reordering flips knife-edge spikes (absmax
// 0.124 fails). Only grid decomposition is parametrized here (nmt m-tiles).
// 128x128 tile, 4 waves of 64x64, K-step 32, 48 KB LDS, 2 blocks/CU.
// A: fp32 X -> regs (1 K-step prefetch) -> cvt_pk_bf16 residual chain ->
// ds_write. B: GLDS from pre-split Wp. Raw s_barrier + counted vmcnt(4).
// XCD-chunked remap (R3, FETCH -72%).
__global__ __launch_bounds__(256, 2) void gemm_fused(
    const float* __restrict__ Xf,            // [nmt*128][512] fp32
    const unsigned short* __restrict__ Wp,   // [3][1024][512] bf16 planes
    const float* __restrict__ b1, const float* __restrict__ b2,
    float* __restrict__ d1buf, float* __restrict__ d2buf, int nmt)
{
    __shared__ unsigned short lds[6][128][32];   // A1,A2,A3,B1,B2,B3 (linear)
    unsigned short* lflat = &lds[0][0][0];
    const int tid  = threadIdx.x;
    const int lane = tid & 63;
    const int w    = tid >> 6;
    // XCD-chunked remap: nmt*8 blocks = 8 chunks x nmt (bijective).
    const int wg = (blockIdx.x & 7) * nmt + (blockIdx.x >> 3);
    const int pm = wg >> 3;             // 0..nmt-1 over M
    const int pn = wg & 7;              // 0..7 over N=1024 (fast -> A reuse)
    const int m0 = pm * 128;
    const int n0 = pn * 128;

    // ---- B staging (GLDS): 24 segments of 1 KB (16 rows x 32 cols), 6/wave
    const unsigned short* gpb[6];
    unsigned lofb[6];
    {
        const int rsub = lane >> 2;          // row within 16-row segment
        const int csub = (lane & 3) * 8;     // ushort offset within row
#pragma unroll
        for (int j = 0; j < 6; ++j) {
            int s = w * 6 + j;               // 0..23
            int p = s >> 3, sub = s & 7;
            gpb[j] = Wp + ((size_t)p * 1024 + n0 + sub * 16 + rsub) * IN + csub;
            lofb[j] = 12288u + (unsigned)s * 512;   // B region starts plane 3
        }
    }

    // ---- A staging (regs): thread -> row = tid>>1, k-half = tid&1
    const int arow  = tid >> 1;
    const int ahalf = tid & 1;
    const float* ga = Xf + (size_t)(m0 + arow) * IN + ahalf * 16;
    const int awbase = arow * 32 + ahalf * 16;   // ushort index within plane

    floatx4 acc[4][4];
#pragma unroll
    for (int i = 0; i < 4; ++i)
#pragma unroll
        for (int j = 0; j < 4; ++j) acc[i][j] = (floatx4){0.f, 0.f, 0.f, 0.f};

    const int wm = w >> 1, wn = w & 1;
    const int c16 = lane & 15;
    const int q8  = (lane >> 4) * 8;

#define LOADA(DST, T) do {                                           \
    _Pragma("unroll")                                                \
    for (int q = 0; q < 4; ++q)                                      \
        DST[q] = *(const floatx4*)(ga + (T) * 32 + q * 4);           \
    } while (0)

    // split 16 fp32 -> 3 planes x 16 bf16, linear ds_write (R5 verbatim)
#define SPLITW(SRC) do {                                             \
    unsigned w1[8], w2[8], w3[8];                                    \
    _Pragma("unroll")                                                \
    for (int q = 0; q < 4; ++q) {                                    \
        _Pragma("unroll")                                            \
        for (int e = 0; e < 2; ++e) {                                \
            float x0 = SRC[q][e * 2], x1 = SRC[q][e * 2 + 1];        \
            unsigned pk1, pk2, pk3;                                  \
            CVTPK(pk1, x0, x1);                                      \
            float r0 = x0 - __uint_as_float(pk1 << 16);              \
            float r1 = x1 - __uint_as_float(pk1 & 0xFFFF0000u);      \
            CVTPK(pk2, r0, r1);                                      \
            float s0 = r0 - __uint_as_float(pk2 << 16);              \
            float s1 = r1 - __uint_as_float(pk2 & 0xFFFF0000u);      \
            CVTPK(pk3, s0, s1);                                      \
            w1[q * 2 + e] = pk1; w2[q * 2 + e] = pk2; w3[q * 2 + e] = pk3; \
        }                                                            \
    }                                                                \
    *(uintx4*)(lflat + awbase)            = (uintx4){w1[0], w1[1], w1[2], w1[3]}; \
    *(uintx4*)(lflat + awbase + 8)        = (uintx4){w1[4], w1[5], w1[6], w1[7]}; \
    *(uintx4*)(lflat + 4096 + awbase)     = (uintx4){w2[0], w2[1], w2[2], w2[3]}; \
    *(uintx4*)(lflat + 4096 + awbase + 8) = (uintx4){w2[4], w2[5], w2[6], w2[7]}; \
    *(uintx4*)(lflat + 8192 + awbase)     = (uintx4){w3[0], w3[1], w3[2], w3[3]}; \
    *(uintx4*)(lflat + 8192 + awbase + 8) = (uintx4){w3[4], w3[5], w3[6], w3[7]}; \
    } while (0)

    // R5-verbatim COMPUTE: 16x16x32, order a3b1,a2b2,a1b3,a2b1,a1b2,a1b1
#define COMPUTE() do {                                               \
    short8 Bf[3][4];                                                 \
    _Pragma("unroll")                                                \
    for (int p = 0; p < 3; ++p)                                      \
        _Pragma("unroll")                                            \
        for (int fj = 0; fj < 4; ++fj)                               \
            Bf[p][fj] = *(const short8*)&lds[3 + p][wn * 64 + fj * 16 + c16][q8]; \
    _Pragma("unroll")                                                \
    for (int fi = 0; fi < 4; ++fi) {                                 \
        const int r = wm * 64 + fi * 16 + c16;                       \
        short8 a1 = *(const short8*)&lds[0][r][q8];                  \
        short8 a2 = *(const short8*)&lds[1][r][q8];                  \
        short8 a3 = *(const short8*)&lds[2][r][q8];                  \
        _Pragma("unroll")                                            \
        for (int fj = 0; fj < 4; ++fj) {                             \
            floatx4 c = acc[fi][fj];                                 \
            c = __builtin_amdgcn_mfma_f32_16x16x32_bf16(a3, Bf[0][fj], c, 0, 0, 0); \
            c = __builtin_amdgcn_mfma_f32_16x16x32_bf16(a2, Bf[1][fj], c, 0, 0, 0); \
            c = __builtin_amdgcn_mfma_f32_16x16x32_bf16(a1, Bf[2][fj], c, 0, 0, 0); \
            c = __builtin_amdgcn_mfma_f32_16x16x32_bf16(a2, Bf[0][fj], c, 0, 0, 0); \
            c = __builtin_amdgcn_mfma_f32_16x16x32_bf16(a1, Bf[1][fj], c, 0, 0, 0); \
            c = __builtin_amdgcn_mfma_f32_16x16x32_bf16(a1, Bf[0][fj], c, 0, 0, 0); \
            acc[fi][fj] = c;                                         \
        }                                                            \
    } } while (0)

#define BAR() asm volatile("s_barrier" ::: "memory")

    floatx4 xa[4], xb[4];
    LOADA(xa, 0);                        // prefetch K-step 0

#pragma unroll 1
    for (int tp = 0; tp < 8; ++tp) {
        const int t0 = tp * 2, t1 = tp * 2 + 1;
        // ---- stage even step (regs xa), prefetch t1 into xb
#pragma unroll
        for (int j = 0; j < 6; ++j) GLDS(gpb[j] + t0 * 32, lflat + lofb[j]);
        LOADA(xb, t1);
        SPLITW(xa);
        asm volatile("s_waitcnt vmcnt(4) lgkmcnt(0)" ::: "memory");
        BAR();
        COMPUTE();
        BAR();
        // ---- stage odd step (regs xb), prefetch t1+1 into xa
#pragma unroll
        for (int j = 0; j < 6; ++j) GLDS(gpb[j] + t1 * 32, lflat + lofb[j]);
        if (tp < 7) LOADA(xa, t1 + 1);
        SPLITW(xb);
        if (tp < 7) asm volatile("s_waitcnt vmcnt(4) lgkmcnt(0)" ::: "memory");
        else        asm volatile("s_waitcnt vmcnt(0) lgkmcnt(0)" ::: "memory");
        BAR();
        COMPUTE();
        BAR();
    }
#undef LOADA
#undef SPLITW
#undef COMPUTE
#undef BAR

    // epilogue: C layout col=lane&15, row=(lane>>4)*4+reg (m89-verified)
    const int quad = lane >> 4;
    const bool first = (n0 < HD);
    const float* bias = first ? b1 : b2;
    float* obuf = first ? d1buf : d2buf;
    const int nb = n0 & (HD - 1);
    float bv[4];
#pragma unroll
    for (int fj = 0; fj < 4; ++fj) bv[fj] = bias[nb + wn * 64 + fj * 16 + c16];
#pragma unroll
    for (int fi = 0; fi < 4; ++fi) {
#pragma unroll
        for (int fj = 0; fj < 4; ++fj) {
            int n = nb + wn * 64 + fj * 16 + c16;
#pragma unroll
            for (int r = 0; r < 4; ++r) {
                int m = m0 + wm * 64 + fi * 16 + quad * 4 + r;
                obuf[(size_t)m * HD + n] = acc[fi][fj][r] + bv[fj];
            }
        }
    }
}

// ---------------- Scan: full T per (b,h); nb batches per dispatch -----------
// 2-group register ping-pong prefetch (R3, +14 us measured).
#define LOADG(g, A1, A2) do {                                        \
    _Pragma("unroll")                                                \
    for (int i = 0; i < 16; ++i) {                                   \
        A1[i] = p1[(size_t)((g) * 16 + i) * HD];                     \
        A2[i] = p2[(size_t)((g) * 16 + i) * HD];                     \
    } } while (0)

#define COMPG(g, A1, A2) do {                                        \
    unsigned int wq = 0;                                             \
    _Pragma("unroll")                                                \
    for (int i = 0; i < 16; ++i) {                                   \
        d1 = be1 * d1 + (1.f - be1) * A1[i];                         \
        d2 = be2 * d2 + (1.f - be2) * A2[i];                         \
        float tot = d1 + d2;                                         \
        mem = mem * alpha + (1.f - alpha) * tot - spk;               \
        bool fire = (mem - 1.0f) > 0.f;                              \
        spk = fire ? 1.f : 0.f;                                      \
        wq |= (fire ? 1u : 0u) << i;                                 \
    }                                                                \
    sp[(size_t)(g) * HD] = (unsigned short)wq; } while (0)

__global__ __launch_bounds__(64) void scan_k(
    const float* __restrict__ d1buf, const float* __restrict__ d2buf,
    const float* __restrict__ tau_m, const float* __restrict__ tau_n1,
    const float* __restrict__ tau_n2,
    const float* __restrict__ mem0, const float* __restrict__ spike0,
    unsigned short* __restrict__ spikes, int b0)
{
    const int gid = blockIdx.x * 64 + threadIdx.x;
    const int h  = gid & (HD - 1);
    const int bl = gid >> 9;                          // local batch index
    const int b  = b0 + bl;
    const float alpha = 1.f / (1.f + expf(-tau_m[h]));
    const float be1   = 1.f / (1.f + expf(-tau_n1[h]));
    const float be2   = 1.f / (1.f + expf(-tau_n2[h]));
    float mem = mem0[b * HD + h];
    float spk = spike0[b * HD + h];
    float d1 = 0.f, d2 = 0.f;
    const float* p1 = d1buf + (size_t)bl * TT * HD + h;
    const float* p2 = d2buf + (size_t)bl * TT * HD + h;
    unsigned short* sp = spikes + (size_t)b * (TT / 16) * HD + h;

    float a1A[16], a2A[16], a1B[16], a2B[16];
    LOADG(0, a1A, a2A);
#pragma unroll 1
    for (int g = 0; g < 48; g += 2) {       // 49 groups total (0..48)
        LOADG(g + 1, a1B, a2B);
        COMPG(g,     a1A, a2A);
        LOADG(g + 2, a1A, a2A);             // g+2 <= 48 always (g <= 46)
        COMPG(g + 1, a1B, a2B);
    }
    COMPG(48, a1A, a2A);
}

// ---------------- Readout (ushort8-vectorized; FMA order bit-identical) -----
__global__ __launch_bounds__(256) void readout(
    const unsigned short* __restrict__ spikes,
    const float* __restrict__ Wr, const float* __restrict__ br,
    float* __restrict__ out)
{
    __shared__ float WrS[10 * HD];   // 20 KB, layout [o][h]
    __shared__ float brS[10];
    const int tid = threadIdx.x;
    for (int i = tid; i < 10 * HD; i += 256) WrS[i] = Wr[i];
    if (tid < 10) brS[tid] = br[tid];
    __syncthreads();

    const int gid = blockIdx.x * 256 + tid;      // 0..100351 = b*784+t
    const int t = gid % TT;
    const int b = gid / TT;
    const int tw  = t >> 4;
    const int bit = t & 15;
    const ushort8* row8 = (const ushort8*)(spikes +
        ((size_t)b * (TT / 16) + tw) * HD);      // 1 KB row, 16B-aligned

    float acc[10];
#pragma unroll
    for (int o = 0; o < 10; ++o) acc[o] = brS[o];

#pragma unroll 1
    for (int hh = 0; hh < HD / 8; ++hh) {
        ushort8 v = row8[hh];
#pragma unroll
        for (int j = 0; j < 8; ++j) {
            float s = (float)((v[j] >> bit) & 1);
            const int h = hh * 8 + j;
#pragma unroll
            for (int o = 0; o < 10; ++o) acc[o] = fmaf(s, WrS[o * HD + h], acc[o]);
        }
    }
    float* op = out + (size_t)gid * 10;
#pragma unroll
    for (int o = 0; o < 10; ++o) op[o] = acc[o];
}

// ---------------------------------------------------------------------------
extern "C" void kernel_launch(void* const* d_in, const int* in_sizes, int n_in,
                              void* d_out, int out_size, void* d_ws, size_t ws_size,
                              hipStream_t stream)
{
    const float* X      = (const float*)d_in[0];
    const float* W1     = (const float*)d_in[1];
    const float* b1     = (const float*)d_in[2];
    const float* W2     = (const float*)d_in[3];
    const float* b2     = (const float*)d_in[4];
    const float* tau_m  = (const float*)d_in[5];
    const float* tau_n1 = (const float*)d_in[6];
    const float* tau_n2 = (const float*)d_in[7];
    const float* Wr     = (const float*)d_in[8];
    const float* br     = (const float*)d_in[9];
    const float* mem0   = (const float*)d_in[10];
    const float* spike0 = (const float*)d_in[11];
    float* out = (float*)d_out;

    const size_t WPB   = (size_t)3 * 1024 * IN * 2;    // Wp bytes (3.1 MB)
    const size_t DFULL = (size_t)MF * HD * 4;          // 205.5 MB full batch
    const size_t DHALF = (size_t)MH * HD * 4;          // 102.8 MB half batch
    const size_t SPB   = (size_t)BB * (TT / 16) * HD * 2;  // 6.4 MB
    const size_t WPS   = (size_t)1024 * IN;            // W plane stride (elems)

    const bool full = ws_size >= WPB + 2 * DFULL + SPB;

    char* p = (char*)d_ws;
    unsigned short* Wp = (unsigned short*)p;  p += WPB;
    float* d1buf = (float*)p;                 p += full ? DFULL : DHALF;
    float* d2buf = (float*)p;                 p += full ? DFULL : DHALF;
    unsigned short* spikes = (unsigned short*)p;

    // split W1 (plane rows 0..511) and W2 (rows 512..1023)
    split3<<<dim3(128), dim3(256), 0, stream>>>(
        W1, Wp, Wp + WPS, Wp + 2 * WPS, (long)HD * IN / 8);
    split3<<<dim3(128), dim3(256), 0, stream>>>(
        W2, Wp + (size_t)HD * IN, Wp + WPS + (size_t)HD * IN,
        Wp + 2 * WPS + (size_t)HD * IN, (long)HD * IN / 8);

    if (full) {
        // single full-batch gemm (784 m-tiles) + single full-batch scan
        gemm_fused<<<dim3(784 * 8), dim3(256), 0, stream>>>(
            X, Wp, b1, b2, d1buf, d2buf, 784);
        scan_k<<<dim3(1024), dim3(64), 0, stream>>>(
            d1buf, d2buf, tau_m, tau_n1, tau_n2, mem0, spike0, spikes, 0);
    } else {
        for (int half = 0; half < 2; ++half) {
            gemm_fused<<<dim3(392 * 8), dim3(256), 0, stream>>>(
                X + (size_t)half * MH * IN, Wp, b1, b2, d1buf, d2buf, 392);
            scan_k<<<dim3(512), dim3(64), 0, stream>>>(
                d1buf, d2buf, tau_m, tau_n1, tau_n2, mem0, spike0,
                spikes, half * 64);
        }
    }
    readout<<<dim3(BB * TT / 256), dim3(256), 0, stream>>>(spikes, Wr, br, out);
}